// Round 6
// baseline (1684.656 us; speedup 1.0000x reference)
//
#include <hip/hip_runtime.h>
#include <hip/hip_cooperative_groups.h>
#include <math.h>

namespace cg = cooperative_groups;

#define HDIM 4096
#define ODIM 50257
#define NTHR 256
#define CBLK 2048   // cooperative grid: 8 blocks/CU on 256 CUs

typedef float f32x4 __attribute__((ext_vector_type(4)));

// ---------- helpers ----------

__device__ __forceinline__ float dot_row(const float* __restrict__ Wrow,
                                         const f32x4* __restrict__ vs,
                                         int lane) {
    const f32x4* w4 = reinterpret_cast<const f32x4*>(Wrow);
    float acc0 = 0.f, acc1 = 0.f;
#pragma unroll
    for (int t = 0; t < 16; t += 2) {
        f32x4 a0 = __builtin_nontemporal_load(&w4[t * 64 + lane]);
        f32x4 b0 = vs[t * 64 + lane];
        f32x4 a1 = __builtin_nontemporal_load(&w4[(t + 1) * 64 + lane]);
        f32x4 b1 = vs[(t + 1) * 64 + lane];
        acc0 = fmaf(a0.x, b0.x, acc0);
        acc0 = fmaf(a0.y, b0.y, acc0);
        acc0 = fmaf(a0.z, b0.z, acc0);
        acc0 = fmaf(a0.w, b0.w, acc0);
        acc1 = fmaf(a1.x, b1.x, acc1);
        acc1 = fmaf(a1.y, b1.y, acc1);
        acc1 = fmaf(a1.z, b1.z, acc1);
        acc1 = fmaf(a1.w, b1.w, acc1);
    }
    float v = acc0 + acc1;
#pragma unroll
    for (int off = 32; off > 0; off >>= 1) v += __shfl_down(v, off, 64);
    return v;  // valid on lane 0
}

__device__ __forceinline__ void stage_v(f32x4* vs, const float* __restrict__ v) {
    const f32x4* v4 = reinterpret_cast<const f32x4*>(v);
#pragma unroll
    for (int i = 0; i < 4; ++i)
        vs[i * NTHR + threadIdx.x] = v4[i * NTHR + threadIdx.x];
}

__device__ __forceinline__ float gate_one(const float* __restrict__ gi,
                                          const float* __restrict__ gh,
                                          float hprev, int j) {
    float r = 1.f / (1.f + expf(-(gi[j] + gh[j])));
    float z = 1.f / (1.f + expf(-(gi[HDIM + j] + gh[HDIM + j])));
    float n = tanhf(gi[2 * HDIM + j] + r * gh[2 * HDIM + j]);
    return (1.f - z) * n + z * hprev;
}

__device__ __forceinline__ void lse_absorb(float& m, float& s, float mo, float so) {
    if (mo > m) { s = s * expf(m - mo) + so; m = mo; }
    else        { s += so * expf(mo - m); }
}

// ---------- cooperative persistent kernel (2048 blocks, 8/CU) ----------

__global__ __launch_bounds__(NTHR, 8) void mega(
    const float* __restrict__ x, const float* __restrict__ h0,
    const float* __restrict__ w_ih1, const float* __restrict__ w_hh1,
    const float* __restrict__ b_ih1, const float* __restrict__ b_hh1,
    const float* __restrict__ w_ih2, const float* __restrict__ w_hh2,
    const float* __restrict__ b_ih2, const float* __restrict__ b_hh2,
    const float* __restrict__ w_out, const float* __restrict__ b_out,
    float* __restrict__ out, float* __restrict__ ws) {
    cg::grid_group grid = cg::this_grid();
    __shared__ f32x4 vs[HDIM / 4];          // 16 KB
    __shared__ float smx[4], ssm[4], lds_lc;

    float* gi1 = ws;
    float* gh1 = ws + 12288;
    float* gi2 = ws + 24576;
    float* gh2 = ws + 36864;
    float* h1  = ws + 49152;
    float* act = ws + 53248;
    float2* pairs = (float2*)(ws + 57344);  // CBLK float2
    float* h2g = out + ODIM;

    const int bid = blockIdx.x, tid = threadIdx.x;
    const int wid = tid >> 6, lane = tid & 63;

    // ---- Phase A: layer-1 GEMVs (blocks 0-1023: w_ih1*x, 1024-2047: w_hh1*h0)
    {
        const bool hi = bid >= (CBLK / 2);
        const float* W  = hi ? w_hh1 : w_ih1;
        const float* vv = hi ? h0 : x;
        const float* bb = hi ? b_hh1 : b_ih1;
        float* o = hi ? gh1 : gi1;
        const int blk = bid & (CBLK / 2 - 1);
        stage_v(vs, vv);
        __syncthreads();
        const int row0 = blk * 12 + wid * 3;
#pragma unroll
        for (int r = 0; r < 3; ++r) {
            int row = row0 + r;
            float d = dot_row(&W[(size_t)row * HDIM], vs, lane);
            if (lane == 0) o[row] = d + bb[row];
        }
    }
    grid.sync();

    // ---- Phase B: GRU gate 1 (blocks 0-15)
    if (bid < 16) {
        int j = bid * NTHR + tid;
        h1[j] = gate_one(gi1, gh1, h0[j], j);
    }
    grid.sync();

    // ---- Phase C: layer-2 GEMVs (v = h1 both halves)
    {
        const bool hi = bid >= (CBLK / 2);
        const float* W  = hi ? w_hh2 : w_ih2;
        const float* bb = hi ? b_hh2 : b_ih2;
        float* o = hi ? gh2 : gi2;
        const int blk = bid & (CBLK / 2 - 1);
        stage_v(vs, h1);
        __syncthreads();
        const int row0 = blk * 12 + wid * 3;
#pragma unroll
        for (int r = 0; r < 3; ++r) {
            int row = row0 + r;
            float d = dot_row(&W[(size_t)row * HDIM], vs, lane);
            if (lane == 0) o[row] = d + bb[row];
        }
    }
    grid.sync();

    // ---- Phase D: GRU gate 2 (blocks 0-15)
    if (bid < 16) {
        int j = bid * NTHR + tid;
        float h2 = gate_one(gi2, gh2, h1[j], j);
        h2g[j] = h2;
        act[j] = fmaxf(h2, 0.f);
    }
    grid.sync();

    // ---- Phase E: logits GEMV + per-block online LSE
    {
        stage_v(vs, act);
        __syncthreads();
        // 50257 = 2048*24 + 1105
        const int start = bid * 24 + min(bid, 1105);
        const int cnt   = 24 + (bid < 1105 ? 1 : 0);
        const int wq = cnt >> 2, wr = cnt & 3;
        const int woff = wid * wq + min(wid, wr);
        const int wcnt = wq + (wid < wr ? 1 : 0);
        float m = -INFINITY, s = 0.f;
        for (int r = 0; r < wcnt; ++r) {
            int row = start + woff + r;
            float d = dot_row(&w_out[(size_t)row * HDIM], vs, lane);
            if (lane == 0) {
                float val = d + b_out[row];
                out[row] = val;
                if (val > m) { s = s * expf(m - val) + 1.f; m = val; }
                else         { s += expf(val - m); }
            }
        }
        if (lane == 0) { smx[wid] = m; ssm[wid] = s; }
        __syncthreads();
        if (tid == 0) {
            float M = smx[0], S = ssm[0];
#pragma unroll
            for (int i = 1; i < 4; ++i) lse_absorb(M, S, smx[i], ssm[i]);
            pairs[bid] = make_float2(M, S);
        }
    }
    grid.sync();

    // ---- Phase F: every block reduces the 2048 pairs, subtracts its slice
    {
        float m = -INFINITY, s = 0.f;
#pragma unroll
        for (int i = 0; i < CBLK / NTHR; ++i) {
            float2 p = pairs[tid + i * NTHR];
            lse_absorb(m, s, p.x, p.y);
        }
#pragma unroll
        for (int off = 32; off > 0; off >>= 1) {
            float mo = __shfl_down(m, off, 64);
            float so = __shfl_down(s, off, 64);
            lse_absorb(m, s, mo, so);
        }
        if (lane == 0) { smx[wid] = m; ssm[wid] = s; }
        __syncthreads();
        if (tid == 0) {
            float M = smx[0], S = ssm[0];
#pragma unroll
            for (int i = 1; i < 4; ++i) lse_absorb(M, S, smx[i], ssm[i]);
            lds_lc = M + logf(S);
        }
        __syncthreads();
        const float logC = lds_lc;
        int i = bid * NTHR + tid;
        if (i < ODIM) out[i] -= logC;
    }
}

// ---------- fallback kernels (proven R3 path) ----------

__global__ __launch_bounds__(NTHR) void gemv_dual(
    const float* __restrict__ Wa, const float* __restrict__ va,
    const float* __restrict__ ba, float* __restrict__ oa,
    const float* __restrict__ Wb, const float* __restrict__ vb,
    const float* __restrict__ bb, float* __restrict__ ob) {
    __shared__ f32x4 vs[HDIM / 4];
    const bool isB = blockIdx.x >= (CBLK / 2);
    const float* W  = isB ? Wb : Wa;
    const float* v  = isB ? vb : va;
    const float* bs = isB ? bb : ba;
    float*       o  = isB ? ob : oa;
    const int blk = isB ? (int)blockIdx.x - CBLK / 2 : (int)blockIdx.x;

    stage_v(vs, v);
    __syncthreads();

    const int wid = threadIdx.x >> 6, lane = threadIdx.x & 63;
    const int row0 = blk * 12 + wid * 3;
#pragma unroll
    for (int r = 0; r < 3; ++r) {
        int row = row0 + r;
        float d = dot_row(&W[(size_t)row * HDIM], vs, lane);
        if (lane == 0) o[row] = d + bs[row];
    }
}

__global__ void gru_gate(const float* __restrict__ gi, const float* __restrict__ gh,
                         const float* __restrict__ hprev, float* __restrict__ hout,
                         float* __restrict__ act) {
    int j = blockIdx.x * blockDim.x + threadIdx.x;
    if (j < HDIM) {
        float h = gate_one(gi, gh, hprev[j], j);
        hout[j] = h;
        if (act) act[j] = fmaxf(h, 0.f);
    }
}

__global__ __launch_bounds__(NTHR) void gemv_logits_lse(
    const float* __restrict__ W, const float* __restrict__ v,
    const float* __restrict__ bias, float* __restrict__ out,
    float2* __restrict__ pairs) {
    __shared__ f32x4 vs[HDIM / 4];
    __shared__ float smx[4], ssm[4];

    stage_v(vs, v);
    __syncthreads();

    const int b = blockIdx.x;
    const int start = b * 24 + min(b, 1105);
    const int cnt   = 24 + (b < 1105 ? 1 : 0);
    const int wid = threadIdx.x >> 6, lane = threadIdx.x & 63;
    const int wq = cnt >> 2, wr = cnt & 3;
    const int woff = wid * wq + min(wid, wr);
    const int wcnt = wq + (wid < wr ? 1 : 0);

    float m = -INFINITY, s = 0.f;
    for (int r = 0; r < wcnt; ++r) {
        int row = start + woff + r;
        float d = dot_row(&W[(size_t)row * HDIM], vs, lane);
        if (lane == 0) {
            float val = d + bias[row];
            out[row] = val;
            if (val > m) { s = s * expf(m - val) + 1.f; m = val; }
            else         { s += expf(val - m); }
        }
    }
    if (lane == 0) { smx[wid] = m; ssm[wid] = s; }
    __syncthreads();
    if (threadIdx.x == 0) {
        float M = smx[0], S = ssm[0];
#pragma unroll
        for (int i = 1; i < 4; ++i) lse_absorb(M, S, smx[i], ssm[i]);
        pairs[b] = make_float2(M, S);
    }
}

__global__ __launch_bounds__(NTHR) void logsm_final(
    float* __restrict__ out, const float2* __restrict__ pairs) {
    __shared__ float smx[4], ssm[4];
    __shared__ float lc;
    float m = -INFINITY, s = 0.f;
    for (int i = threadIdx.x; i < CBLK; i += NTHR) {
        float2 p = pairs[i];
        lse_absorb(m, s, p.x, p.y);
    }
#pragma unroll
    for (int off = 32; off > 0; off >>= 1) {
        float mo = __shfl_down(m, off, 64);
        float so = __shfl_down(s, off, 64);
        lse_absorb(m, s, mo, so);
    }
    const int wid = threadIdx.x >> 6, lane = threadIdx.x & 63;
    if (lane == 0) { smx[wid] = m; ssm[wid] = s; }
    __syncthreads();
    if (threadIdx.x == 0) {
        float M = smx[0], S = ssm[0];
#pragma unroll
        for (int i = 1; i < 4; ++i) lse_absorb(M, S, smx[i], ssm[i]);
        lc = M + logf(S);
    }
    __syncthreads();
    float logC = lc;
    for (int i = blockIdx.x * NTHR + threadIdx.x; i < ODIM; i += gridDim.x * NTHR)
        out[i] -= logC;
}

// ---------- launch ----------

extern "C" void kernel_launch(void* const* d_in, const int* in_sizes, int n_in,
                              void* d_out, int out_size, void* d_ws, size_t ws_size,
                              hipStream_t stream) {
    const float* x     = (const float*)d_in[0];
    const float* h0    = (const float*)d_in[1];
    const float* w_ih1 = (const float*)d_in[2];
    const float* w_hh1 = (const float*)d_in[3];
    const float* b_ih1 = (const float*)d_in[4];
    const float* b_hh1 = (const float*)d_in[5];
    const float* w_ih2 = (const float*)d_in[6];
    const float* w_hh2 = (const float*)d_in[7];
    const float* b_ih2 = (const float*)d_in[8];
    const float* b_hh2 = (const float*)d_in[9];
    const float* w_out = (const float*)d_in[10];
    const float* b_out = (const float*)d_in[11];
    float* out = (float*)d_out;
    float* ws  = (float*)d_ws;

    void* args[] = {
        (void*)&x, (void*)&h0,
        (void*)&w_ih1, (void*)&w_hh1, (void*)&b_ih1, (void*)&b_hh1,
        (void*)&w_ih2, (void*)&w_hh2, (void*)&b_ih2, (void*)&b_hh2,
        (void*)&w_out, (void*)&b_out,
        (void*)&out, (void*)&ws
    };
    hipError_t err = hipLaunchCooperativeKernel((const void*)mega, dim3(CBLK),
                                                dim3(NTHR), args, 0, stream);
    if (err == hipSuccess) return;
    (void)hipGetLastError();  // clear sticky error from the rejected launch

    // fallback: proven 6-kernel path
    float* gi1  = ws;
    float* gh1  = ws + 12288;
    float* gi2  = ws + 24576;
    float* gh2  = ws + 36864;
    float* h1   = ws + 49152;
    float* act  = ws + 53248;
    float2* pairs = (float2*)(ws + 57344);
    float* h2_out = out + ODIM;

    gemv_dual<<<CBLK, NTHR, 0, stream>>>(w_ih1, x, b_ih1, gi1,
                                         w_hh1, h0, b_hh1, gh1);
    gru_gate<<<HDIM / NTHR, NTHR, 0, stream>>>(gi1, gh1, h0, h1, nullptr);
    gemv_dual<<<CBLK, NTHR, 0, stream>>>(w_ih2, h1, b_ih2, gi2,
                                         w_hh2, h1, b_hh2, gh2);
    gru_gate<<<HDIM / NTHR, NTHR, 0, stream>>>(gi2, gh2, h1, h2_out, act);
    gemv_logits_lse<<<CBLK, NTHR, 0, stream>>>(w_out, act, b_out, out, pairs);
    logsm_final<<<64, NTHR, 0, stream>>>(out, pairs);
}

// Round 7
// 603.889 us; speedup vs baseline: 2.7897x; 2.7897x over previous
//
#include <hip/hip_runtime.h>
#include <hip/hip_cooperative_groups.h>
#include <math.h>

namespace cg = cooperative_groups;

#define HDIM 4096
#define ODIM 50257
#define NTHR 256
#define GMAX 2048   // hard cap on coop grid (pairs buffer sized for this)
#define FBLK 2048   // fallback big-GEMV grid

typedef float f32x4 __attribute__((ext_vector_type(4)));

// ---------- helpers ----------

__device__ __forceinline__ float dot_row(const float* __restrict__ Wrow,
                                         const f32x4* __restrict__ vs,
                                         int lane) {
    const f32x4* w4 = reinterpret_cast<const f32x4*>(Wrow);
    float acc0 = 0.f, acc1 = 0.f;
#pragma unroll
    for (int t = 0; t < 16; t += 2) {
        f32x4 a0 = __builtin_nontemporal_load(&w4[t * 64 + lane]);
        f32x4 b0 = vs[t * 64 + lane];
        f32x4 a1 = __builtin_nontemporal_load(&w4[(t + 1) * 64 + lane]);
        f32x4 b1 = vs[(t + 1) * 64 + lane];
        acc0 = fmaf(a0.x, b0.x, acc0);
        acc0 = fmaf(a0.y, b0.y, acc0);
        acc0 = fmaf(a0.z, b0.z, acc0);
        acc0 = fmaf(a0.w, b0.w, acc0);
        acc1 = fmaf(a1.x, b1.x, acc1);
        acc1 = fmaf(a1.y, b1.y, acc1);
        acc1 = fmaf(a1.z, b1.z, acc1);
        acc1 = fmaf(a1.w, b1.w, acc1);
    }
    float v = acc0 + acc1;
#pragma unroll
    for (int off = 32; off > 0; off >>= 1) v += __shfl_down(v, off, 64);
    return v;  // valid on lane 0
}

__device__ __forceinline__ void stage_v(f32x4* vs, const float* __restrict__ v) {
    const f32x4* v4 = reinterpret_cast<const f32x4*>(v);
#pragma unroll
    for (int i = 0; i < 4; ++i)
        vs[i * NTHR + threadIdx.x] = v4[i * NTHR + threadIdx.x];
}

__device__ __forceinline__ float gate_one(const float* __restrict__ gi,
                                          const float* __restrict__ gh,
                                          float hprev, int j) {
    float r = 1.f / (1.f + expf(-(gi[j] + gh[j])));
    float z = 1.f / (1.f + expf(-(gi[HDIM + j] + gh[HDIM + j])));
    float n = tanhf(gi[2 * HDIM + j] + r * gh[2 * HDIM + j]);
    return (1.f - z) * n + z * hprev;
}

__device__ __forceinline__ void lse_absorb(float& m, float& s, float mo, float so) {
    if (mo > m) { s = s * expf(m - mo) + so; m = mo; }
    else        { s += so * expf(mo - m); }
}

// ---------- cooperative persistent kernel (grid-stride, any grid size) ----------

__global__ __launch_bounds__(NTHR) void mega(
    const float* __restrict__ x, const float* __restrict__ h0,
    const float* __restrict__ w_ih1, const float* __restrict__ w_hh1,
    const float* __restrict__ b_ih1, const float* __restrict__ b_hh1,
    const float* __restrict__ w_ih2, const float* __restrict__ w_hh2,
    const float* __restrict__ b_ih2, const float* __restrict__ b_hh2,
    const float* __restrict__ w_out, const float* __restrict__ b_out,
    float* __restrict__ out, float* __restrict__ ws) {
    cg::grid_group grid = cg::this_grid();
    __shared__ f32x4 vs[HDIM / 4];          // 16 KB
    __shared__ float smx[4], ssm[4], lds_lc;

    float* gi1 = ws;
    float* gh1 = ws + 12288;
    float* gi2 = ws + 24576;
    float* gh2 = ws + 36864;
    float* h1  = ws + 49152;
    float* act = ws + 53248;
    float2* pairs = (float2*)(ws + 57344);  // up to GMAX float2
    float* h2g = out + ODIM;

    const int G   = (int)gridDim.x;
    const int bid = blockIdx.x, tid = threadIdx.x;
    const int wid = tid >> 6, lane = tid & 63;
    const int half = G >> 1;
    const bool hi  = bid >= half;
    const int  lb  = hi ? bid - half : bid;   // local block within half
    const int  NWH = half * 4;                // waves per half
    const int  wh  = lb * 4 + wid;            // wave id within half

    // ---- Phase A: layer-1 GEMVs (low half: w_ih1*x -> gi1, high: w_hh1*h0 -> gh1)
    {
        const float* W  = hi ? w_hh1 : w_ih1;
        const float* bb = hi ? b_hh1 : b_ih1;
        float* o = hi ? gh1 : gi1;
        stage_v(vs, hi ? h0 : x);
        __syncthreads();
        for (int r = wh; r < 3 * HDIM; r += NWH) {
            float d = dot_row(&W[(size_t)r * HDIM], vs, lane);
            if (lane == 0) o[r] = d + bb[r];
        }
    }
    grid.sync();

    // ---- Phase B: GRU gate 1 (blocks 0-15)
    if (bid < 16) {
        int j = bid * NTHR + tid;
        h1[j] = gate_one(gi1, gh1, h0[j], j);
    }
    grid.sync();

    // ---- Phase C: layer-2 GEMVs (v = h1 both halves)
    {
        const float* W  = hi ? w_hh2 : w_ih2;
        const float* bb = hi ? b_hh2 : b_ih2;
        float* o = hi ? gh2 : gi2;
        stage_v(vs, h1);
        __syncthreads();
        for (int r = wh; r < 3 * HDIM; r += NWH) {
            float d = dot_row(&W[(size_t)r * HDIM], vs, lane);
            if (lane == 0) o[r] = d + bb[r];
        }
    }
    grid.sync();

    // ---- Phase D: GRU gate 2 (blocks 0-15)
    if (bid < 16) {
        int j = bid * NTHR + tid;
        float h2 = gate_one(gi2, gh2, h1[j], j);
        h2g[j] = h2;
        act[j] = fmaxf(h2, 0.f);
    }
    grid.sync();

    // ---- Phase E: logits GEMV + per-block online LSE (grid-stride by wave)
    {
        stage_v(vs, act);
        __syncthreads();
        const int NW = G * 4;
        float m = -INFINITY, s = 0.f;
        for (int r = bid * 4 + wid; r < ODIM; r += NW) {
            float d = dot_row(&w_out[(size_t)r * HDIM], vs, lane);
            if (lane == 0) {
                float val = d + b_out[r];
                out[r] = val;
                if (val > m) { s = s * expf(m - val) + 1.f; m = val; }
                else         { s += expf(val - m); }
            }
        }
        if (lane == 0) { smx[wid] = m; ssm[wid] = s; }
        __syncthreads();
        if (tid == 0) {
            float M = smx[0], S = ssm[0];
#pragma unroll
            for (int i = 1; i < 4; ++i) lse_absorb(M, S, smx[i], ssm[i]);
            pairs[bid] = make_float2(M, S);
        }
    }
    grid.sync();

    // ---- Phase F: every block reduces the G pairs, subtracts its slice
    {
        float m = -INFINITY, s = 0.f;
        for (int i = tid; i < G; i += NTHR) {
            float2 p = pairs[i];
            lse_absorb(m, s, p.x, p.y);
        }
#pragma unroll
        for (int off = 32; off > 0; off >>= 1) {
            float mo = __shfl_down(m, off, 64);
            float so = __shfl_down(s, off, 64);
            lse_absorb(m, s, mo, so);
        }
        if (lane == 0) { smx[wid] = m; ssm[wid] = s; }
        __syncthreads();
        if (tid == 0) {
            float M = smx[0], S = ssm[0];
#pragma unroll
            for (int i = 1; i < 4; ++i) lse_absorb(M, S, smx[i], ssm[i]);
            lds_lc = M + logf(S);
        }
        __syncthreads();
        const float logC = lds_lc;
        for (int i = bid * NTHR + tid; i < ODIM; i += G * NTHR)
            out[i] -= logC;
    }
}

// ---------- fallback kernels (proven R3 path) ----------

__global__ __launch_bounds__(NTHR) void gemv_dual(
    const float* __restrict__ Wa, const float* __restrict__ va,
    const float* __restrict__ ba, float* __restrict__ oa,
    const float* __restrict__ Wb, const float* __restrict__ vb,
    const float* __restrict__ bb, float* __restrict__ ob) {
    __shared__ f32x4 vs[HDIM / 4];
    const bool isB = blockIdx.x >= (FBLK / 2);
    const float* W  = isB ? Wb : Wa;
    const float* v  = isB ? vb : va;
    const float* bs = isB ? bb : ba;
    float*       o  = isB ? ob : oa;
    const int blk = isB ? (int)blockIdx.x - FBLK / 2 : (int)blockIdx.x;

    stage_v(vs, v);
    __syncthreads();

    const int wid = threadIdx.x >> 6, lane = threadIdx.x & 63;
    const int row0 = blk * 12 + wid * 3;
#pragma unroll
    for (int r = 0; r < 3; ++r) {
        int row = row0 + r;
        float d = dot_row(&W[(size_t)row * HDIM], vs, lane);
        if (lane == 0) o[row] = d + bs[row];
    }
}

__global__ void gru_gate(const float* __restrict__ gi, const float* __restrict__ gh,
                         const float* __restrict__ hprev, float* __restrict__ hout,
                         float* __restrict__ act) {
    int j = blockIdx.x * blockDim.x + threadIdx.x;
    if (j < HDIM) {
        float h = gate_one(gi, gh, hprev[j], j);
        hout[j] = h;
        if (act) act[j] = fmaxf(h, 0.f);
    }
}

__global__ __launch_bounds__(NTHR) void gemv_logits_lse(
    const float* __restrict__ W, const float* __restrict__ v,
    const float* __restrict__ bias, float* __restrict__ out,
    float2* __restrict__ pairs) {
    __shared__ f32x4 vs[HDIM / 4];
    __shared__ float smx[4], ssm[4];

    stage_v(vs, v);
    __syncthreads();

    const int b = blockIdx.x;
    const int start = b * 24 + min(b, 1105);
    const int cnt   = 24 + (b < 1105 ? 1 : 0);
    const int wid = threadIdx.x >> 6, lane = threadIdx.x & 63;
    const int wq = cnt >> 2, wr = cnt & 3;
    const int woff = wid * wq + min(wid, wr);
    const int wcnt = wq + (wid < wr ? 1 : 0);

    float m = -INFINITY, s = 0.f;
    for (int r = 0; r < wcnt; ++r) {
        int row = start + woff + r;
        float d = dot_row(&W[(size_t)row * HDIM], vs, lane);
        if (lane == 0) {
            float val = d + bias[row];
            out[row] = val;
            if (val > m) { s = s * expf(m - val) + 1.f; m = val; }
            else         { s += expf(val - m); }
        }
    }
    if (lane == 0) { smx[wid] = m; ssm[wid] = s; }
    __syncthreads();
    if (threadIdx.x == 0) {
        float M = smx[0], S = ssm[0];
#pragma unroll
        for (int i = 1; i < 4; ++i) lse_absorb(M, S, smx[i], ssm[i]);
        pairs[b] = make_float2(M, S);
    }
}

__global__ __launch_bounds__(NTHR) void logsm_final(
    float* __restrict__ out, const float2* __restrict__ pairs) {
    __shared__ float smx[4], ssm[4];
    __shared__ float lc;
    float m = -INFINITY, s = 0.f;
    for (int i = threadIdx.x; i < FBLK; i += NTHR) {
        float2 p = pairs[i];
        lse_absorb(m, s, p.x, p.y);
    }
#pragma unroll
    for (int off = 32; off > 0; off >>= 1) {
        float mo = __shfl_down(m, off, 64);
        float so = __shfl_down(s, off, 64);
        lse_absorb(m, s, mo, so);
    }
    const int wid = threadIdx.x >> 6, lane = threadIdx.x & 63;
    if (lane == 0) { smx[wid] = m; ssm[wid] = s; }
    __syncthreads();
    if (threadIdx.x == 0) {
        float M = smx[0], S = ssm[0];
#pragma unroll
        for (int i = 1; i < 4; ++i) lse_absorb(M, S, smx[i], ssm[i]);
        lc = M + logf(S);
    }
    __syncthreads();
    float logC = lc;
    for (int i = blockIdx.x * NTHR + threadIdx.x; i < ODIM; i += gridDim.x * NTHR)
        out[i] -= logC;
}

// ---------- launch ----------

extern "C" void kernel_launch(void* const* d_in, const int* in_sizes, int n_in,
                              void* d_out, int out_size, void* d_ws, size_t ws_size,
                              hipStream_t stream) {
    const float* x     = (const float*)d_in[0];
    const float* h0    = (const float*)d_in[1];
    const float* w_ih1 = (const float*)d_in[2];
    const float* w_hh1 = (const float*)d_in[3];
    const float* b_ih1 = (const float*)d_in[4];
    const float* b_hh1 = (const float*)d_in[5];
    const float* w_ih2 = (const float*)d_in[6];
    const float* w_hh2 = (const float*)d_in[7];
    const float* b_ih2 = (const float*)d_in[8];
    const float* b_hh2 = (const float*)d_in[9];
    const float* w_out = (const float*)d_in[10];
    const float* b_out = (const float*)d_in[11];
    float* out = (float*)d_out;
    float* ws  = (float*)d_ws;

    // runtime-computed co-residency capacity (deterministic, no stream ops)
    int maxBlk = 0;
    hipError_t qerr = hipOccupancyMaxActiveBlocksPerMultiprocessor(
        &maxBlk, (const void*)mega, NTHR, 0);

    if (qerr == hipSuccess && maxBlk >= 2) {
        int G = maxBlk * 256;           // 256 CUs on MI355X
        if (G > GMAX) G = GMAX;
        G &= ~1;                        // even (half-split)
        void* args[] = {
            (void*)&x, (void*)&h0,
            (void*)&w_ih1, (void*)&w_hh1, (void*)&b_ih1, (void*)&b_hh1,
            (void*)&w_ih2, (void*)&w_hh2, (void*)&b_ih2, (void*)&b_hh2,
            (void*)&w_out, (void*)&b_out,
            (void*)&out, (void*)&ws
        };
        hipError_t err = hipLaunchCooperativeKernel((const void*)mega, dim3(G),
                                                    dim3(NTHR), args, 0, stream);
        if (err == hipSuccess) return;
        (void)hipGetLastError();  // clear sticky error, fall through
    } else {
        (void)hipGetLastError();
    }

    // fallback: proven 6-kernel path
    float* gi1  = ws;
    float* gh1  = ws + 12288;
    float* gi2  = ws + 24576;
    float* gh2  = ws + 36864;
    float* h1   = ws + 49152;
    float* act  = ws + 53248;
    float2* pairs = (float2*)(ws + 57344);
    float* h2_out = out + ODIM;

    gemv_dual<<<FBLK, NTHR, 0, stream>>>(w_ih1, x, b_ih1, gi1,
                                         w_hh1, h0, b_hh1, gh1);
    gru_gate<<<HDIM / NTHR, NTHR, 0, stream>>>(gi1, gh1, h0, h1, nullptr);
    gemv_dual<<<FBLK, NTHR, 0, stream>>>(w_ih2, h1, b_ih2, gi2,
                                         w_hh2, h1, b_hh2, gh2);
    gru_gate<<<HDIM / NTHR, NTHR, 0, stream>>>(gi2, gh2, h1, h2_out, act);
    gemv_logits_lse<<<FBLK, NTHR, 0, stream>>>(w_out, act, b_out, out, pairs);
    logsm_final<<<64, NTHR, 0, stream>>>(out, pairs);
}

// Round 8
// 278.010 us; speedup vs baseline: 6.0597x; 2.1722x over previous
//
#include <hip/hip_runtime.h>
#include <math.h>

#define HDIM 4096
#define ODIM 50257
#define NTHR 256
#define GBLK 2048   // big-GEMV grid

typedef float f32x4 __attribute__((ext_vector_type(4)));

// ---------- helpers ----------

__device__ __forceinline__ float sigm(float v) { return 1.f / (1.f + expf(-v)); }

__device__ __forceinline__ float dot_row(const float* __restrict__ Wrow,
                                         const f32x4* __restrict__ vs,
                                         int lane) {
    const f32x4* w4 = reinterpret_cast<const f32x4*>(Wrow);
    float acc0 = 0.f, acc1 = 0.f;
#pragma unroll
    for (int t = 0; t < 16; t += 2) {
        f32x4 a0 = __builtin_nontemporal_load(&w4[t * 64 + lane]);
        f32x4 b0 = vs[t * 64 + lane];
        f32x4 a1 = __builtin_nontemporal_load(&w4[(t + 1) * 64 + lane]);
        f32x4 b1 = vs[(t + 1) * 64 + lane];
        acc0 = fmaf(a0.x, b0.x, acc0);
        acc0 = fmaf(a0.y, b0.y, acc0);
        acc0 = fmaf(a0.z, b0.z, acc0);
        acc0 = fmaf(a0.w, b0.w, acc0);
        acc1 = fmaf(a1.x, b1.x, acc1);
        acc1 = fmaf(a1.y, b1.y, acc1);
        acc1 = fmaf(a1.z, b1.z, acc1);
        acc1 = fmaf(a1.w, b1.w, acc1);
    }
    float v = acc0 + acc1;
#pragma unroll
    for (int off = 32; off > 0; off >>= 1) v += __shfl_down(v, off, 64);
    return v;  // valid on lane 0
}

__device__ __forceinline__ void stage_v(f32x4* vs, const float* __restrict__ v) {
    const f32x4* v4 = reinterpret_cast<const f32x4*>(v);
#pragma unroll
    for (int i = 0; i < 4; ++i)
        vs[i * NTHR + threadIdx.x] = v4[i * NTHR + threadIdx.x];
}

// Redundant per-block GRU gate: h = (1-z)*n + z*hprev, staged into vs.
// If do_relu, vs gets relu(h); if hg != nullptr, raw h is stored to global.
__device__ __forceinline__ void gate_stage(const float* __restrict__ gi,
                                           const float* __restrict__ gh,
                                           const float* __restrict__ hprev,
                                           f32x4* vs, bool do_relu,
                                           float* __restrict__ hg) {
    const f32x4* gir = (const f32x4*)gi;
    const f32x4* giz = (const f32x4*)(gi + HDIM);
    const f32x4* gin = (const f32x4*)(gi + 2 * HDIM);
    const f32x4* ghr = (const f32x4*)gh;
    const f32x4* ghz = (const f32x4*)(gh + HDIM);
    const f32x4* ghn = (const f32x4*)(gh + 2 * HDIM);
    const f32x4* hp4 = (const f32x4*)hprev;
    for (int i = threadIdx.x; i < HDIM / 4; i += NTHR) {
        f32x4 ar = gir[i], br = ghr[i];
        f32x4 az = giz[i], bz = ghz[i];
        f32x4 an = gin[i], bn = ghn[i];
        f32x4 hv = hp4[i];
        f32x4 h;
#pragma unroll
        for (int k = 0; k < 4; ++k) {
            float r = sigm(ar[k] + br[k]);
            float z = sigm(az[k] + bz[k]);
            float n = tanhf(an[k] + r * bn[k]);
            h[k] = (1.f - z) * n + z * hv[k];
        }
        if (hg) ((f32x4*)hg)[i] = h;
        if (do_relu) {
#pragma unroll
            for (int k = 0; k < 4; ++k) h[k] = fmaxf(h[k], 0.f);
        }
        vs[i] = h;
    }
}

__device__ __forceinline__ void lse_absorb(float& m, float& s, float mo, float so) {
    if (mo > m) { s = s * expf(m - mo) + so; m = mo; }
    else        { s += so * expf(mo - m); }
}

// GEMV body over 12 contiguous rows per block (3 per wave)
__device__ __forceinline__ void gemv12(const float* __restrict__ W,
                                       const float* __restrict__ bs,
                                       float* __restrict__ o, int blk,
                                       const f32x4* vs) {
    const int wid = threadIdx.x >> 6, lane = threadIdx.x & 63;
    const int row0 = blk * 12 + wid * 3;
#pragma unroll
    for (int r = 0; r < 3; ++r) {
        int row = row0 + r;
        float d = dot_row(&W[(size_t)row * HDIM], vs, lane);
        if (lane == 0) o[row] = d + bs[row];
    }
}

// ---------- kernels ----------

// K1: layer-1 dual GEMV (stage v from global directly)
__global__ __launch_bounds__(NTHR) void gemv_l1(
    const float* __restrict__ Wa, const float* __restrict__ va,
    const float* __restrict__ ba, float* __restrict__ oa,
    const float* __restrict__ Wb, const float* __restrict__ vb,
    const float* __restrict__ bb, float* __restrict__ ob) {
    __shared__ f32x4 vs[HDIM / 4];
    const bool isB = blockIdx.x >= (GBLK / 2);
    stage_v(vs, isB ? vb : va);
    __syncthreads();
    const int blk = isB ? (int)blockIdx.x - GBLK / 2 : (int)blockIdx.x;
    gemv12(isB ? Wb : Wa, isB ? bb : ba, isB ? ob : oa, blk, vs);
}

// K2: layer-2 dual GEMV with gate-1 fused (v = h1 computed in-block)
__global__ __launch_bounds__(NTHR) void gemv_l2_fused(
    const float* __restrict__ Wa, const float* __restrict__ ba, float* __restrict__ oa,
    const float* __restrict__ Wb, const float* __restrict__ bb, float* __restrict__ ob,
    const float* __restrict__ gi1, const float* __restrict__ gh1,
    const float* __restrict__ h0, float* __restrict__ h1g) {
    __shared__ f32x4 vs[HDIM / 4];
    gate_stage(gi1, gh1, h0, vs, false, blockIdx.x == 0 ? h1g : nullptr);
    __syncthreads();
    const bool isB = blockIdx.x >= (GBLK / 2);
    const int blk = isB ? (int)blockIdx.x - GBLK / 2 : (int)blockIdx.x;
    gemv12(isB ? Wb : Wa, isB ? bb : ba, isB ? ob : oa, blk, vs);
}

// K3: logits GEMV with gate-2 fused (v = relu(h2)) + per-block online LSE
__global__ __launch_bounds__(NTHR) void gemv_logits_fused(
    const float* __restrict__ W, const float* __restrict__ bias,
    const float* __restrict__ gi2, const float* __restrict__ gh2,
    const float* __restrict__ h1g, float* __restrict__ out,
    float* __restrict__ h2g, float2* __restrict__ pairs) {
    __shared__ f32x4 vs[HDIM / 4];
    __shared__ float smx[4], ssm[4];
    gate_stage(gi2, gh2, h1g, vs, true, blockIdx.x == 0 ? h2g : nullptr);
    __syncthreads();

    const int b = blockIdx.x;
    const int start = b * 24 + min(b, 1105);   // 50257 = 2048*24 + 1105
    const int cnt   = 24 + (b < 1105 ? 1 : 0);
    const int wid = threadIdx.x >> 6, lane = threadIdx.x & 63;
    const int wq = cnt >> 2, wr = cnt & 3;
    const int woff = wid * wq + min(wid, wr);
    const int wcnt = wq + (wid < wr ? 1 : 0);

    float m = -INFINITY, s = 0.f;
    for (int r = 0; r < wcnt; ++r) {
        int row = start + woff + r;
        float d = dot_row(&W[(size_t)row * HDIM], vs, lane);
        if (lane == 0) {
            float val = d + bias[row];
            out[row] = val;
            if (val > m) { s = s * expf(m - val) + 1.f; m = val; }
            else         { s += expf(val - m); }
        }
    }
    if (lane == 0) { smx[wid] = m; ssm[wid] = s; }
    __syncthreads();
    if (threadIdx.x == 0) {
        float M = smx[0], S = ssm[0];
#pragma unroll
        for (int i = 1; i < 4; ++i) lse_absorb(M, S, smx[i], ssm[i]);
        pairs[b] = make_float2(M, S);
    }
}

// K4: reduce pairs -> logC (redundant per block), subtract over slice
__global__ __launch_bounds__(NTHR) void logsm_final(
    float* __restrict__ out, const float2* __restrict__ pairs) {
    __shared__ float smx[4], ssm[4];
    __shared__ float lc;
    float m = -INFINITY, s = 0.f;
    for (int i = threadIdx.x; i < GBLK; i += NTHR) {
        float2 p = pairs[i];
        lse_absorb(m, s, p.x, p.y);
    }
#pragma unroll
    for (int off = 32; off > 0; off >>= 1) {
        float mo = __shfl_down(m, off, 64);
        float so = __shfl_down(s, off, 64);
        lse_absorb(m, s, mo, so);
    }
    const int wid = threadIdx.x >> 6, lane = threadIdx.x & 63;
    if (lane == 0) { smx[wid] = m; ssm[wid] = s; }
    __syncthreads();
    if (threadIdx.x == 0) {
        float M = smx[0], S = ssm[0];
#pragma unroll
        for (int i = 1; i < 4; ++i) lse_absorb(M, S, smx[i], ssm[i]);
        lc = M + logf(S);
    }
    __syncthreads();
    float logC = lc;
    for (int i = blockIdx.x * NTHR + threadIdx.x; i < ODIM; i += gridDim.x * NTHR)
        out[i] -= logC;
}

// ---------- launch ----------

extern "C" void kernel_launch(void* const* d_in, const int* in_sizes, int n_in,
                              void* d_out, int out_size, void* d_ws, size_t ws_size,
                              hipStream_t stream) {
    const float* x     = (const float*)d_in[0];
    const float* h0    = (const float*)d_in[1];
    const float* w_ih1 = (const float*)d_in[2];
    const float* w_hh1 = (const float*)d_in[3];
    const float* b_ih1 = (const float*)d_in[4];
    const float* b_hh1 = (const float*)d_in[5];
    const float* w_ih2 = (const float*)d_in[6];
    const float* w_hh2 = (const float*)d_in[7];
    const float* b_ih2 = (const float*)d_in[8];
    const float* b_hh2 = (const float*)d_in[9];
    const float* w_out = (const float*)d_in[10];
    const float* b_out = (const float*)d_in[11];

    float* out    = (float*)d_out;        // log_softmax [50257]
    float* h2_out = out + ODIM;           // h2 [4096]

    float* ws   = (float*)d_ws;
    float* gi1  = ws;                     // 12288
    float* gh1  = ws + 12288;             // 12288
    float* gi2  = ws + 24576;             // 12288
    float* gh2  = ws + 36864;             // 12288
    float* h1g  = ws + 49152;             // 4096
    float2* pairs = (float2*)(ws + 57344);// 2048 float2

    gemv_l1<<<GBLK, NTHR, 0, stream>>>(w_ih1, x, b_ih1, gi1,
                                       w_hh1, h0, b_hh1, gh1);
    gemv_l2_fused<<<GBLK, NTHR, 0, stream>>>(w_ih2, b_ih2, gi2,
                                             w_hh2, b_hh2, gh2,
                                             gi1, gh1, h0, h1g);
    gemv_logits_fused<<<GBLK, NTHR, 0, stream>>>(w_out, b_out, gi2, gh2,
                                                 h1g, out, h2_out, pairs);
    logsm_final<<<64, NTHR, 0, stream>>>(out, pairs);
}